// Round 12
// baseline (297.100 us; speedup 1.0000x reference)
//
#include <hip/hip_runtime.h>
#include <math.h>

// ---------------------------------------------------------------------------
// GATPolicy: 3x GATConv (with self loops) + mean-pool + MLP head.
// CSR-by-dst with ZERO global atomics (r1: device-scope atomicAdd bypasses
// the non-coherent XCD L2s; 56us). r9 structure (259us) + r10 agg-consume
// rework: the LDS-staged {w0,w1,rowoff} broadcast (half0/half1 addrs 128B
// apart = same-bank 2-way conflict on EVERY consume read; 800k/dispatch) is
// replaced by segment-relative __shfl(v, k, 32) — in-register per-half
// broadcast, zero LDS — and the gather batch is deepened 8 -> 16 loads in
// flight (halves the vmcnt(0) latency exposures; h gathers miss the 4MB
// per-XCD L2 ~1/3 of the time at FETCH 34MB).
// (r10/r11 bench attempts hit "container failed twice" broker errors before
// the kernel ever ran; source re-audited fault-free, resubmitted unchanged
// for a clean A/B vs r9.)
//   P1    hist | transform0 | W pack | gstart     (1 dispatch)
//   scanA histT -> offs (2 small dispatches)
//   P3    partition (LDS ranks, LDS-cached offs col) -> esrc/dsub8
//   P4    per-bucket: count -> scan -> row_ptr -> col
//   agg2t<128,2> layer0 agg + fused MFMA transform1 (hA,as0 -> hB,as1)
//   agg2t<64,1>  layer1 agg + fused MFMA transform2 (hB,as1 -> hA,as2)
//   agg1  layer2 agg -> xbuf
//   mlp   pool-fused head (gstart, 512 thr)
// AGG core: 2 nodes/wave (32-lane half per node); lane l gathers dword =
// ch{2l,2l+1}x2 heads (fp8-interleaved). agg2t epilogue: agg out -> LDS
// xs[16][136] (bf16, b128-aligned, 2-way-free) -> per-wave 16-col MFMA tile
// -> fp8 hN + LDS-reduced asN/adN (ping-pong A<->B buffers).
// (r13: never chain blocks across XCDs. r6/r7: don't fuse the offs scan.)
// ---------------------------------------------------------------------------

#define LRELU(x) ((x) > 0.f ? (x) : 0.2f * (x))

typedef short bf16x8 __attribute__((ext_vector_type(8)));
typedef unsigned short u16x8 __attribute__((ext_vector_type(8)));
typedef float f32x4 __attribute__((ext_vector_type(4)));
typedef float f32x2 __attribute__((ext_vector_type(2)));

__device__ __forceinline__ unsigned short f2bf(float f) {
    unsigned int u = __float_as_uint(f);
    u = (u + 0x7fffu + ((u >> 16) & 1u)) >> 16;  // RNE
    return (unsigned short)u;
}
__device__ __forceinline__ float bf2f(unsigned short u) {
    return __uint_as_float((unsigned int)u << 16);
}
__device__ __forceinline__ unsigned char f2fp8(float f) {
    return (unsigned char)(__builtin_amdgcn_cvt_pk_fp8_f32(f, f, 0, false) & 0xff);
}
__device__ __forceinline__ f32x2 fp8pair(unsigned int u) {
    return __builtin_amdgcn_cvt_pk_f32_fp8(u, false);  // bytes 0,1
}

// fp8 h byte position for channel c: 2-head interleaved pairs, 1-head flat
template <int OUT, int HEADS>
__device__ __forceinline__ int hpos8(int c) {
    return (HEADS == 2) ? (2 * (c & 63) + (c >> 6)) : c;
}

// -- P1: bucket hist (2048-edge chunks) || transform0 || W pack || gstart ---

__global__ __launch_bounds__(256) void hist_t0_kernel(
    const int* __restrict__ dst, int* __restrict__ histT,
    int e, int G1, int NB, int n, int hist_blocks, int t0_blocks, int wp_blocks,
    const float* __restrict__ x, const float* __restrict__ W,
    const float* __restrict__ a_src, const float* __restrict__ a_dst,
    unsigned char* __restrict__ h, float* __restrict__ as_o,
    float* __restrict__ ad_o,
    const float* __restrict__ W1, const float* __restrict__ W2,
    unsigned short* __restrict__ Wf1, unsigned short* __restrict__ Wf2,
    const int* __restrict__ batch, int* __restrict__ gstart, int nGraphs) {
    __shared__ unsigned int hist[256];
    __shared__ float xs[2][8][8];
    const int t = threadIdx.x;
    if ((int)blockIdx.x < hist_blocks) {
        hist[t] = 0;
        __syncthreads();
        int base = blockIdx.x * 2048 + t * 8;
        int d[8];
        if (base + 8 <= e) {
            int4 x0 = *(const int4*)(dst + base);
            int4 x1 = *(const int4*)(dst + base + 4);
            d[0] = x0.x; d[1] = x0.y; d[2] = x0.z; d[3] = x0.w;
            d[4] = x1.x; d[5] = x1.y; d[6] = x1.z; d[7] = x1.w;
        } else {
#pragma unroll
            for (int j = 0; j < 8; j++) {
                int ij = base + j;
                d[j] = (ij < e) ? dst[ij] : -1;
            }
        }
#pragma unroll
        for (int j = 0; j < 8; j++) {
            if (d[j] >= 0) atomicAdd(&hist[d[j] >> 8], 1u);
        }
        __syncthreads();
        if (t < NB) histT[t * G1 + blockIdx.x] = (int)hist[t];
        return;
    }
    if ((int)blockIdx.x < hist_blocks + t0_blocks) {
        // ---- transform0 path: h(fp8)=x@W0, as/ad. 16 nodes/block ----
        const int bid2 = blockIdx.x - hist_blocks;
        const int tid = t & 127;
        const int half = t >> 7;
        const int node0 = bid2 * 16 + half * 8;

        for (int idx = tid; idx < 64; idx += 128) {
            int ni = idx >> 3, k = idx & 7;
            int ng = node0 + ni;
            xs[half][ni][k] = (ng < n) ? x[(size_t)ng * 8 + k] : 0.f;
        }
        __syncthreads();

        float acc[8];
#pragma unroll
        for (int i = 0; i < 8; i++) acc[i] = 0.f;
#pragma unroll
        for (int k = 0; k < 8; k++) {
            float wk = W[k * 128 + tid];
#pragma unroll
            for (int i = 0; i < 8; i++) acc[i] += xs[half][i][k] * wk;
        }

        const int lane = tid & 63;
        const int head = tid >> 6;
        const int pos = 2 * lane + head;  // 2-head interleaved fp8 byte pos
        const float av = a_src[tid];
        const float dv = a_dst[tid];
#pragma unroll
        for (int i = 0; i < 8; i++) {
            int ng = node0 + i;
            if (ng >= n) break;
            h[(size_t)ng * 128 + pos] = f2fp8(acc[i]);
            float ps = acc[i] * av, pd = acc[i] * dv;
            for (int off = 32; off; off >>= 1) {
                ps += __shfl_xor(ps, off, 64);
                pd += __shfl_xor(pd, off, 64);
            }
            if (lane == 0) {
                as_o[ng * 2 + head] = ps;
                ad_o[ng * 2 + head] = pd;
            }
        }
        return;
    }
    if ((int)blockIdx.x < hist_blocks + t0_blocks + wp_blocks) {
        // ---- W pack path ----
        const int n1 = 8 * 4 * 64;   // W1 fragment rows (OUT=128)
        const int n2 = 4 * 4 * 64;   // W2 fragment rows (OUT=64)
        int gid = (blockIdx.x - hist_blocks - t0_blocks) * 256 + t;
        if (gid < n1) {
            int idx = gid;
            int lane = idx & 63, ts = idx >> 6;
            int s = ts & 3, tt = ts >> 2;
            int quad = lane >> 4, cn = lane & 15;
#pragma unroll
            for (int j = 0; j < 8; j++)
                Wf1[idx * 8 + j] = f2bf(W1[(s * 32 + quad * 8 + j) * 128 + tt * 16 + cn]);
        } else if (gid < n1 + n2) {
            int idx = gid - n1;
            int lane = idx & 63, ts = idx >> 6;
            int s = ts & 3, tt = ts >> 2;
            int quad = lane >> 4, cn = lane & 15;
#pragma unroll
            for (int j = 0; j < 8; j++)
                Wf2[idx * 8 + j] = f2bf(W2[(s * 32 + quad * 8 + j) * 64 + tt * 16 + cn]);
        }
        return;
    }
    // ---- gstart path: graph boundaries of sorted batch ----
    int gid = (blockIdx.x - hist_blocks - t0_blocks - wp_blocks) * 256 + t;
    if (gid < n) {
        int bi = batch[gid];
        if (gid == 0) {
            for (int g = 0; g <= bi; g++) gstart[g] = 0;
        } else {
            int bp = batch[gid - 1];
            if (bi != bp)
                for (int g = bp + 1; g <= bi; g++) gstart[g] = gid;
        }
        if (gid == n - 1) {
            for (int g = bi + 1; g <= nGraphs; g++) gstart[g] = n;
        }
    }
}

// ---------------- generalized scan: 512 elements per block -----------------

__global__ __launch_bounds__(256) void scan2_block_kernel(
    const int* __restrict__ in, int* __restrict__ out,
    int* __restrict__ blockSums, int len) {
    __shared__ int lds[256];
    int t = threadIdx.x;
    int i0 = blockIdx.x * 512 + 2 * t;
    int v0 = (i0 < len) ? in[i0] : 0;
    int v1 = (i0 + 1 < len) ? in[i0 + 1] : 0;
    int s = v0 + v1;
    lds[t] = s;
    __syncthreads();
    for (int off = 1; off < 256; off <<= 1) {
        int u = (t >= off) ? lds[t - off] : 0;
        __syncthreads();
        lds[t] += u;
        __syncthreads();
    }
    int base = lds[t] - s;  // block-local exclusive for element i0
    if (i0 < len) out[i0] = base;
    if (i0 + 1 < len) out[i0 + 1] = base + v0;
    if (t == 255) blockSums[blockIdx.x] = lds[255];
}

// Every block redundantly scans blockSums (nb <= 256) and applies its base.
__global__ __launch_bounds__(256) void scan2_finalize_kernel(
    int* __restrict__ out, const int* __restrict__ blockSums, int len, int nb) {
    __shared__ int lds[256];
    int t = threadIdx.x;
    int v = (t < nb) ? blockSums[t] : 0;
    lds[t] = v;
    __syncthreads();
    for (int off = 1; off < 256; off <<= 1) {
        int u = (t >= off) ? lds[t - off] : 0;
        __syncthreads();
        lds[t] += u;
        __syncthreads();
    }
    const int bid = blockIdx.x;
    const int base = (bid > 0) ? lds[bid - 1] : 0;
    const int total = lds[nb - 1];
    int i0 = bid * 512 + 2 * t;
#pragma unroll
    for (int q = 0; q < 2; q++) {
        int i = i0 + q;
        if (i < len) out[i] += base;
        else if (i == len) out[len] = total;
    }
}

// -- P3: bucket partition (LDS ranks; offs column cached in LDS) ------------

__global__ __launch_bounds__(256) void bucket_scatter_kernel(
    const int* __restrict__ src, const int* __restrict__ dst,
    const int* __restrict__ offs, int* __restrict__ esrc,
    unsigned char* __restrict__ dsub8, int e, int G1, int NB) {
    __shared__ unsigned int hist[256];
    __shared__ int baseL[256];
    const int t = threadIdx.x;
    hist[t] = 0;
    if (t < NB) baseL[t] = offs[t * G1 + blockIdx.x];
    __syncthreads();
    int base = blockIdx.x * 2048 + t * 8;
    int d[8], s[8];
    if (base + 8 <= e) {
        int4 d0 = *(const int4*)(dst + base);
        int4 d1 = *(const int4*)(dst + base + 4);
        int4 s0 = *(const int4*)(src + base);
        int4 s1 = *(const int4*)(src + base + 4);
        d[0] = d0.x; d[1] = d0.y; d[2] = d0.z; d[3] = d0.w;
        d[4] = d1.x; d[5] = d1.y; d[6] = d1.z; d[7] = d1.w;
        s[0] = s0.x; s[1] = s0.y; s[2] = s0.z; s[3] = s0.w;
        s[4] = s1.x; s[5] = s1.y; s[6] = s1.z; s[7] = s1.w;
    } else {
#pragma unroll
        for (int j = 0; j < 8; j++) {
            int ij = base + j;
            bool v = ij < e;
            d[j] = v ? dst[ij] : -1;
            s[j] = v ? src[ij] : 0;
        }
    }
    unsigned lr[8];
#pragma unroll
    for (int j = 0; j < 8; j++) {
        lr[j] = (d[j] >= 0) ? atomicAdd(&hist[d[j] >> 8], 1u) : 0u;
    }
#pragma unroll
    for (int j = 0; j < 8; j++) {
        if (d[j] >= 0) {
            int pos = baseL[d[j] >> 8] + (int)lr[j];
            esrc[pos] = s[j];
            dsub8[pos] = (unsigned char)(d[j] & 255);
        }
    }
}

// -- P4: per-bucket (256 nodes) CSR finalize: count -> scan -> row_ptr -> col

__global__ __launch_bounds__(256) void bucket_csr_kernel(
    const int* __restrict__ offs, const unsigned char* __restrict__ dsub8,
    const int* __restrict__ esrc, int* __restrict__ row_ptr,
    int* __restrict__ col, int G1, int n) {
    __shared__ unsigned int cnt[256];
    __shared__ int rp[256];
    int t = threadIdx.x;
    int b = blockIdx.x;
    cnt[t] = 0;
    __syncthreads();
    int bs = offs[b * G1];
    int be = offs[(b + 1) * G1];
    for (int i = bs + t; i < be; i += 256) {
        atomicAdd(&cnt[dsub8[i]], 1u);
    }
    __syncthreads();
    int v = (int)cnt[t];
    rp[t] = v;
    __syncthreads();
    for (int off = 1; off < 256; off <<= 1) {
        int u = (t >= off) ? rp[t - off] : 0;
        __syncthreads();
        rp[t] += u;
        __syncthreads();
    }
    int excl = rp[t] - v;
    int node = b * 256 + t;
    if (node <= n) row_ptr[node] = bs + excl;  // node==n lands here too (E)
    __syncthreads();
    cnt[t] = (unsigned)excl;  // running cursors
    __syncthreads();
    for (int i = bs + t; i < be; i += 256) {
        int sub = dsub8[i];
        unsigned r = atomicAdd(&cnt[sub], 1u);
        col[bs + (int)r] = esrc[i];
    }
}

// -- agg2t: 2-head agg (2 nodes/wave, 16 nodes/block) + FUSED next-layer ----
// MFMA transform. Consume uses __shfl(v,k,32) per-half broadcast (no LDS
// staging, no bank conflicts) with 16 gather loads in flight.

template <int OUT2, int HEADS2>
__global__ __launch_bounds__(512) void agg2t_kernel(
    const int* __restrict__ row_ptr, const int* __restrict__ col,
    const unsigned char* __restrict__ h, const float2* __restrict__ as2,
    const float2* __restrict__ ad2, const float* __restrict__ bias,
    const unsigned short* __restrict__ Wf, const float* __restrict__ aN_src,
    const float* __restrict__ aN_dst, unsigned char* __restrict__ hN,
    float* __restrict__ asN, float* __restrict__ adN, int n) {
    __shared__ unsigned short xs[16][136];   // 272B row stride: b128-aligned
    __shared__ float asP[16][8], adP[16][8];
    const int w = threadIdx.x >> 6;
    const int lane = threadIdx.x & 63;
    const int half = lane >> 5, l = lane & 31;
    const int node0 = blockIdx.x * 16;
    const int mloc = w * 2 + half;
    const int node = node0 + mloc;
    const bool active = node < n;

    // ---------------- aggregation (2-head, fp8 h) ----------------
    int beg = 0, deg = 0;
    float2 adv = make_float2(0.f, 0.f);
    float den0 = 0.f, den1 = 0.f;
    float a0 = 0.f, a1 = 0.f, a2 = 0.f, a3 = 0.f;
    if (active) {
        beg = row_ptr[node];
        deg = row_ptr[node + 1] - beg;
        adv = ad2[node];
        float2 avs = as2[node];
        float w0s = __expf(LRELU(avs.x + adv.x));
        float w1s = __expf(LRELU(avs.y + adv.y));
        unsigned us = *(const unsigned*)(h + ((size_t)node << 7) + 4 * l);
        f32x2 p0 = fp8pair(us & 0xffffu);
        f32x2 p1 = fp8pair(us >> 16);
        a0 = w0s * p0.x; a1 = w1s * p0.y;
        a2 = w0s * p1.x; a3 = w1s * p1.y;
        den0 = w0s; den1 = w1s;
    }
    int dmax = deg;
    for (int off = 32; off; off >>= 1) dmax = max(dmax, __shfl_xor(dmax, off, 64));

    for (int base = 0; base < dmax; base += 32) {
        int cnt = deg - base;
        cnt = cnt < 0 ? 0 : (cnt > 32 ? 32 : cnt);
        float w0 = 0.f, w1 = 0.f;
        unsigned so = 0;
        if (l < cnt) {
            int s = col[beg + base + l];
            float2 av = as2[s];
            w0 = __expf(LRELU(av.x + adv.x));
            w1 = __expf(LRELU(av.y + adv.y));
            so = (unsigned)s << 7;
        }
        float t0 = w0, t1 = w1;
        for (int off = 16; off; off >>= 1) {
            t0 += __shfl_xor(t0, off, 64);
            t1 += __shfl_xor(t1, off, 64);
        }
        den0 += t0; den1 += t1;

        int jmax = dmax - base;
        jmax = jmax > 32 ? 32 : jmax;
        for (int j = 0; j < jmax; j += 16) {  // pads carry w=0, so=0
            unsigned u[16];
#pragma unroll
            for (int k = 0; k < 16; k++) {
                unsigned so_k = (unsigned)__shfl((int)so, j + k, 32);
                u[k] = *(const unsigned*)(h + so_k + 4 * l);
            }
#pragma unroll
            for (int k = 0; k < 16; k++) {
                float W0k = __shfl(w0, j + k, 32);
                float W1k = __shfl(w1, j + k, 32);
                f32x2 p0 = fp8pair(u[k] & 0xffffu);
                f32x2 p1 = fp8pair(u[k] >> 16);
                a0 += W0k * p0.x; a1 += W1k * p0.y;
                a2 += W0k * p1.x; a3 += W1k * p1.y;
            }
        }
    }

    // epilogue -> LDS (bf16; same quantization as old global xb round-trip)
    if (active) {
        float2 bA = *(const float2*)(bias + 2 * l);
        float2 bB = *(const float2*)(bias + 64 + 2 * l);
        float r0 = 1.f / (den0 + 1e-16f), r1 = 1.f / (den1 + 1e-16f);
        float o0 = a0 * r0 + bA.x;  // ch2l   h0
        float o1 = a1 * r1 + bB.x;  // ch2l   h1
        float o2 = a2 * r0 + bA.y;  // ch2l+1 h0
        float o3 = a3 * r1 + bB.y;  // ch2l+1 h1
        o0 = o0 > 0.f ? o0 : expm1f(o0);
        o1 = o1 > 0.f ? o1 : expm1f(o1);
        o2 = o2 > 0.f ? o2 : expm1f(o2);
        o3 = o3 > 0.f ? o3 : expm1f(o3);
        *(unsigned*)&xs[mloc][2 * l] = (unsigned)f2bf(o0) | ((unsigned)f2bf(o2) << 16);
        *(unsigned*)&xs[mloc][64 + 2 * l] = (unsigned)f2bf(o1) | ((unsigned)f2bf(o3) << 16);
    } else {
        *(unsigned*)&xs[mloc][2 * l] = 0;
        *(unsigned*)&xs[mloc][64 + 2 * l] = 0;
    }
    __syncthreads();

    // ---------------- fused transform: hN = xs @ Wf ----------------
    constexpr int T2 = OUT2 / 16, S = 4;  // K = 128
    const int quad = lane >> 4, colc = lane & 15;
    if (w < T2) {
        bf16x8 a[S];
#pragma unroll
        for (int s = 0; s < S; s++)
            a[s] = *(const bf16x8*)&xs[colc][quad * 8 + s * 32];
        f32x4 acc = (f32x4){0.f, 0.f, 0.f, 0.f};
#pragma unroll
        for (int s = 0; s < S; s++) {
            bf16x8 b = *(const bf16x8*)(Wf + ((size_t)(w * S + s) * 64 + lane) * 8);
            acc = __builtin_amdgcn_mfma_f32_16x16x32_bf16(a[s], b, acc, 0, 0, 0);
        }
        const int pos = hpos8<OUT2, HEADS2>(w * 16 + colc);
#pragma unroll
        for (int r = 0; r < 4; r++) {
            int m = node0 + quad * 4 + r;
            if (m < n) hN[(size_t)m * OUT2 + pos] = f2fp8(acc[r]);
        }
        const float av = aN_src[w * 16 + colc];
        const float dv = aN_dst[w * 16 + colc];
#pragma unroll
        for (int r = 0; r < 4; r++) {
            float sp = acc[r] * av, dp = acc[r] * dv;
            for (int off = 8; off; off >>= 1) {
                sp += __shfl_xor(sp, off, 64);
                dp += __shfl_xor(dp, off, 64);
            }
            if (colc == 0) {
                asP[quad * 4 + r][w] = sp;
                adP[quad * 4 + r][w] = dp;
            }
        }
    }
    __syncthreads();
    const int tt = threadIdx.x;
    if (tt < 16 * HEADS2) {
        int m = tt & 15, head = tt >> 4;
        int node2 = node0 + m;
        if (node2 < n) {
            float s = 0.f, d = 0.f;
#pragma unroll
            for (int ww = 0; ww < 4; ww++) {
                s += asP[m][head * 4 + ww];
                d += adP[m][head * 4 + ww];
            }
            asN[node2 * HEADS2 + head] = s;
            adN[node2 * HEADS2 + head] = d;
        }
    }
}

// ------- GAT aggregation, 1 head (fp8 h, layer 2): two nodes per wave ------
// shfl-broadcast consume, 16 loads in flight. Output bf16 (feeds pool only).

__global__ __launch_bounds__(256) void agg1_kernel(
    const int* __restrict__ row_ptr, const int* __restrict__ col,
    const unsigned char* __restrict__ h, const float* __restrict__ as1,
    const float* __restrict__ ad1, const float* __restrict__ bias,
    unsigned short* __restrict__ out, int n) {
    const int w = threadIdx.x >> 6;
    const int lane = threadIdx.x & 63;
    const int half = lane >> 5, l = lane & 31;
    const int node = blockIdx.x * 8 + w * 2 + half;
    const bool active = node < n;

    int beg = 0, deg = 0;
    float adv = 0.f, den = 0.f, a0 = 0.f, a2 = 0.f;
    if (active) {
        beg = row_ptr[node];
        deg = row_ptr[node + 1] - beg;
        adv = ad1[node];
        float ws = __expf(LRELU(as1[node] + adv));
        unsigned us = *(const unsigned short*)(h + ((size_t)node << 6) + 2 * l);
        f32x2 p = fp8pair(us);
        a0 = ws * p.x;
        a2 = ws * p.y;
        den = ws;
    }
    int dmax = deg;
    for (int off = 32; off; off >>= 1) dmax = max(dmax, __shfl_xor(dmax, off, 64));

    for (int base = 0; base < dmax; base += 32) {
        int cnt = deg - base;
        cnt = cnt < 0 ? 0 : (cnt > 32 ? 32 : cnt);
        float w0 = 0.f;
        unsigned so = 0;
        if (l < cnt) {
            int s = col[beg + base + l];
            w0 = __expf(LRELU(as1[s] + adv));
            so = (unsigned)s << 6;
        }
        float t = w0;
        for (int off = 16; off; off >>= 1) t += __shfl_xor(t, off, 64);
        den += t;

        int jmax = dmax - base;
        jmax = jmax > 32 ? 32 : jmax;
        for (int j = 0; j < jmax; j += 16) {
            unsigned u[16];
#pragma unroll
            for (int k = 0; k < 16; k++) {
                unsigned so_k = (unsigned)__shfl((int)so, j + k, 32);
                u[k] = *(const unsigned short*)(h + so_k + 2 * l);
            }
#pragma unroll
            for (int k = 0; k < 16; k++) {
                float Wk = __shfl(w0, j + k, 32);
                f32x2 p = fp8pair(u[k]);
                a0 += Wk * p.x;
                a2 += Wk * p.y;
            }
        }
    }

    if (active) {
        float2 bA = *(const float2*)(bias + 2 * l);
        float r = 1.f / (den + 1e-16f);
        float o0 = a0 * r + bA.x;
        float o2 = a2 * r + bA.y;
        unsigned hv = (unsigned)f2bf(o0) | ((unsigned)f2bf(o2) << 16);
        *(unsigned*)(out + (size_t)node * 64 + 2 * l) = hv;
    }
}

// ------- MLP head (pool fused): 512 threads/block, one block per graph -----

__global__ __launch_bounds__(512) void mlp_kernel(
    const unsigned short* __restrict__ xbuf, const int* __restrict__ gstart,
    const float* __restrict__ obs,
    const float* __restrict__ Ws1, const float* __restrict__ bs1,
    const float* __restrict__ ln_g, const float* __restrict__ ln_b,
    const float* __restrict__ Ws2, const float* __restrict__ bs2,
    const float* __restrict__ Wa, const float* __restrict__ ba,
    const float* __restrict__ Wc, const float* __restrict__ bc,
    float* __restrict__ out_logits, float* __restrict__ out_value) {
    int b = blockIdx.x;
    int t = threadIdx.x;
    __shared__ float comb[192];
    __shared__ float red[512];
    __shared__ float red2[8][64];
    __shared__ float hs[256];

    const int gs = gstart[b];
    const int ge = gstart[b + 1];

    // ---- pool: 64 rowgroups (8/wave) x 8 chunks of ushort8 ----
    {
        const int w = t >> 6, lane = t & 63;
        const int rg = w * 8 + (lane >> 3);
        const int sub = lane & 7;
        float acc[8];
#pragma unroll
        for (int j = 0; j < 8; j++) acc[j] = 0.f;
        for (int i = gs + rg; i < ge; i += 64) {
            u16x8 v = *(const u16x8*)(xbuf + (size_t)i * 64 + sub * 8);
#pragma unroll
            for (int j = 0; j < 8; j++) acc[j] += bf2f(v[j]);
        }
#pragma unroll
        for (int off = 8; off <= 32; off <<= 1) {
#pragma unroll
            for (int j = 0; j < 8; j++) acc[j] += __shfl_xor(acc[j], off, 64);
        }
        if (lane < 8) {
#pragma unroll
            for (int j = 0; j < 8; j++) red2[w][lane * 8 + j] = acc[j];
        }
    }
    __syncthreads();
    {
        float cdiv = fmaxf((float)(ge - gs), 1.f);
        if (t < 64) {
            float s = 0.f;
#pragma unroll
            for (int w = 0; w < 8; w++) s += red2[w][t];
            comb[t] = s / cdiv;
        } else if (t < 192) {
            comb[t] = obs[b * 128 + (t - 64)];
        }
    }
    __syncthreads();

    const int t256 = t & 255;
    const int khalf = t >> 8;

    // ---- fc1: k split 2x96 ----
    {
        float accA = 0.f, accB = 0.f;
        int k0 = khalf * 96;
#pragma unroll 4
        for (int k = k0; k < k0 + 96; k += 2) {
            accA += comb[k] * Ws1[k * 256 + t256];
            accB += comb[k + 1] * Ws1[(k + 1) * 256 + t256];
        }
        red[t] = accA + accB;
    }
    __syncthreads();
    float acc = 0.f;
    if (t < 256) acc = bs1[t] + red[t] + red[t + 256];
    __syncthreads();

    // ---- LayerNorm over 256 ----
    red[t] = (t < 256) ? acc : 0.f;
    __syncthreads();
    for (int off = 128; off; off >>= 1) {
        if (t < off) red[t] += red[t + off];
        __syncthreads();
    }
    float mu = red[0] / 256.f;
    __syncthreads();
    float d = acc - mu;
    red[t] = (t < 256) ? d * d : 0.f;
    __syncthreads();
    for (int off = 128; off; off >>= 1) {
        if (t < off) red[t] += red[t + off];
        __syncthreads();
    }
    float var = red[0] / 256.f;
    if (t < 256) {
        float hn = d * rsqrtf(var + 1e-5f) * ln_g[t] + ln_b[t];
        hs[t] = hn > 0.f ? hn : 0.f;
    }
    __syncthreads();

    // ---- fc2: k split 2x128 ----
    {
        float a2A = 0.f, a2B = 0.f;
        int k0 = khalf * 128;
#pragma unroll 4
        for (int k = k0; k < k0 + 128; k += 2) {
            a2A += hs[k] * Ws2[k * 256 + t256];
            a2B += hs[k + 1] * Ws2[(k + 1) * 256 + t256];
        }
        red[t] = a2A + a2B;
    }
    __syncthreads();
    float acc2 = 0.f;
    if (t < 256) {
        acc2 = bs2[t] + red[t] + red[t + 256];
        acc2 = acc2 > 0.f ? acc2 : 0.f;
    }
    __syncthreads();
    if (t < 256) hs[t] = acc2;
    __syncthreads();

    // ---- logits: 16 outs x 32 k-chunks of 8 + LDS tree ----
    {
        int o = t & 15, ck = t >> 4;
        float p = 0.f;
#pragma unroll
        for (int k = 0; k < 8; k++)
            p += hs[ck * 8 + k] * Wa[(ck * 8 + k) * 16 + o];
        red[t] = p;
    }
    __syncthreads();
    for (int off = 16; off >= 1; off >>= 1) {
        if ((t >> 4) < off) red[t] += red[t + off * 16];
        __syncthreads();
    }
    if (t < 16) out_logits[b * 16 + t] = red[t] + ba[t];
    __syncthreads();

    // ---- value: full-width dot + tree over 512 ----
    red[t] = (t < 256) ? hs[t] * Wc[t] : 0.f;
    __syncthreads();
    for (int off = 256; off; off >>= 1) {
        if (t < off) red[t] += red[t + off];
        __syncthreads();
    }
    if (t == 0) out_value[b] = red[0] + bc[0];
}

// ---------------------------------------------------------------------------

extern "C" void kernel_launch(void* const* d_in, const int* in_sizes, int n_in,
                              void* d_out, int out_size, void* d_ws, size_t ws_size,
                              hipStream_t stream) {
    const float* obs    = (const float*)d_in[0];
    const float* nf     = (const float*)d_in[1];
    const int*   ei     = (const int*)d_in[2];
    const int*   batch  = (const int*)d_in[3];
    const float* W0     = (const float*)d_in[4];
    const float* a_src0 = (const float*)d_in[5];
    const float* a_dst0 = (const float*)d_in[6];
    const float* b0     = (const float*)d_in[7];
    const float* W1     = (const float*)d_in[8];
    const float* a_src1 = (const float*)d_in[9];
    const float* a_dst1 = (const float*)d_in[10];
    const float* b1     = (const float*)d_in[11];
    const float* W2     = (const float*)d_in[12];
    const float* a_src2 = (const float*)d_in[13];
    const float* a_dst2 = (const float*)d_in[14];
    const float* b2     = (const float*)d_in[15];
    const float* Ws1    = (const float*)d_in[16];
    const float* bs1    = (const float*)d_in[17];
    const float* ln_g   = (const float*)d_in[18];
    const float* ln_b   = (const float*)d_in[19];
    const float* Ws2    = (const float*)d_in[20];
    const float* bs2    = (const float*)d_in[21];
    const float* Wa     = (const float*)d_in[22];
    const float* ba     = (const float*)d_in[23];
    const float* Wc     = (const float*)d_in[24];
    const float* bc     = (const float*)d_in[25];

    const int N = in_sizes[3];
    const int E = in_sizes[2] / 2;
    const int B = in_sizes[0] / 128;
    const int* src = ei;
    const int* dstp = ei + E;

    // workspace carve (256B aligned)
    char* p = (char*)d_ws;
    auto alloc = [&](size_t bytes) -> void* {
        void* r = (void*)p;
        p += (bytes + 255) & ~(size_t)255;
        return r;
    };
    const int G1 = (E + 2047) / 2048;       // edge chunks (2048/block)
    const int NB = (N + 255) >> 8;          // dst buckets of 256 (n <= 65536)
    const int L  = NB * G1;                 // histT length
    int*   row_ptr   = (int*)alloc((size_t)(N + 1) * 4);
    int*   col       = (int*)alloc((size_t)E * 4);
    int*   esrc      = (int*)alloc((size_t)E * 4);           // bucketed src
    unsigned char* dsub8 = (unsigned char*)alloc((size_t)E); // bucketed dst&255
    int*   histT     = (int*)alloc((size_t)L * 4);           // [b][g]
    int*   offs      = (int*)alloc((size_t)(L + 1) * 4);
    unsigned char* hbufA = (unsigned char*)alloc((size_t)N * 128);  // fp8 ping
    unsigned char* hbufB = (unsigned char*)alloc((size_t)N * 128);  // fp8 pong
    unsigned short* xbuf = (unsigned short*)alloc((size_t)N * 64 * 2);  // bf16
    float* as0       = (float*)alloc((size_t)N * 2 * 4);
    float* ad0       = (float*)alloc((size_t)N * 2 * 4);
    float* as1       = (float*)alloc((size_t)N * 2 * 4);
    float* ad1       = (float*)alloc((size_t)N * 2 * 4);
    float* as2v      = (float*)alloc((size_t)N * 4);
    float* ad2v      = (float*)alloc((size_t)N * 4);
    unsigned short* Wf1 = (unsigned short*)alloc((size_t)8 * 4 * 64 * 8 * 2);
    unsigned short* Wf2 = (unsigned short*)alloc((size_t)4 * 4 * 64 * 8 * 2);
    int* gstart      = (int*)alloc((size_t)(B + 1) * 4);
    int* blockSums   = (int*)alloc((size_t)1024 * 4);

    float* out_logits = (float*)d_out;
    float* out_value  = out_logits + (size_t)B * 16;

    // ---- P1: hist || transform0 || W pack || gstart (1 dispatch) ----
    int t0_blocks = (N + 15) / 16;
    int wp_blocks = (8 * 4 * 64 + 4 * 4 * 64 + 255) / 256;
    int gb_blocks = (N + 255) / 256;
    hist_t0_kernel<<<G1 + t0_blocks + wp_blocks + gb_blocks, 256, 0, stream>>>(
        dstp, histT, E, G1, NB, N, G1, t0_blocks, wp_blocks,
        nf, W0, a_src0, a_dst0, hbufA, as0, ad0,
        W1, W2, Wf1, Wf2, batch, gstart, B);

    // ---- scanA over histT -> offs (2 small dispatches) ----
    int nbA = (L + 511) / 512;
    scan2_block_kernel<<<nbA, 256, 0, stream>>>(histT, offs, blockSums, L);
    scan2_finalize_kernel<<<(L + 1 + 511) / 512, 256, 0, stream>>>(offs, blockSums, L, nbA);

    // ---- P3 bucket partition (LDS-cached offs col) + P4 finalize ----
    bucket_scatter_kernel<<<G1, 256, 0, stream>>>(src, dstp, offs, esrc, dsub8, E, G1, NB);
    bucket_csr_kernel<<<NB, 256, 0, stream>>>(offs, dsub8, esrc, row_ptr, col, G1, N);

    // ---- GAT layer 0 agg + fused transform1 (hA,as0 -> hB,as1) ----
    agg2t_kernel<128, 2><<<(N + 15) / 16, 512, 0, stream>>>(
        row_ptr, col, hbufA, (const float2*)as0, (const float2*)ad0, b0,
        Wf1, a_src1, a_dst1, hbufB, as1, ad1, N);

    // ---- GAT layer 1 agg + fused transform2 (hB,as1 -> hA,as2) ----
    agg2t_kernel<64, 1><<<(N + 15) / 16, 512, 0, stream>>>(
        row_ptr, col, hbufB, (const float2*)as1, (const float2*)ad1, b1,
        Wf2, a_src2, a_dst2, hbufA, as2v, ad2v, N);

    // ---- GAT layer 2 aggregation -> xbuf ----
    agg1_kernel<<<(N + 7) / 8, 256, 0, stream>>>(
        row_ptr, col, hbufA, as2v, ad2v, b2, xbuf, N);

    // ---- MLP head with fused mean-pool (1 dispatch, no atomics) ----
    mlp_kernel<<<B, 512, 0, stream>>>(xbuf, gstart, obs, Ws1, bs1, ln_g, ln_b,
                                      Ws2, bs2, Wa, ba, Wc, bc,
                                      out_logits, out_value);
}

// Round 13
// 256.825 us; speedup vs baseline: 1.1568x; 1.1568x over previous
//
#include <hip/hip_runtime.h>
#include <math.h>

// ---------------------------------------------------------------------------
// GATPolicy: 3x GATConv (with self loops) + mean-pool + MLP head.
// CSR-by-dst with ZERO global atomics (r1: device-scope atomicAdd bypasses
// the non-coherent XCD L2s; 56us). r9 structure (259us). r12 LESSON: __shfl
// is ds_bpermute (an LDS op) on gfx950 — replacing the staged LDS broadcast
// with 3 shfls/edge cost MORE (41.5->59us, VALU 55->38%), and 16-deep
// batches cut occupancy 48->37%. The 800k "bank conflicts" are 2-way =
// ~free (m136). REVERTED to r9 staged-broadcast consume (8-deep), with one
// strict improvement: {w0,w1} packed in ONE float2 LDS array -> 2 LDS reads
// per consumed edge (b64+b32) instead of 3.
//   P1    hist | transform0 | W pack | gstart     (1 dispatch)
//   scanA histT -> offs (2 small dispatches)
//   P3    partition (LDS ranks, LDS-cached offs col) -> esrc/dsub8
//   P4    per-bucket: count -> scan -> row_ptr -> col
//   agg2t<128,2> layer0 agg + fused MFMA transform1 (hA,as0 -> hB,as1)
//   agg2t<64,1>  layer1 agg + fused MFMA transform2 (hB,as1 -> hA,as2)
//   agg1  layer2 agg -> xbuf
//   mlp   pool-fused head (gstart, 512 thr)
// AGG core: 2 nodes/wave (32-lane half per node); lane l gathers dword =
// ch{2l,2l+1}x2 heads (fp8-interleaved); 32-edge chunks stage {w01,rowoff}
// to wave-private LDS, consume as uniform-per-half broadcasts, 8 loads in
// flight. agg2t epilogue: agg out -> LDS xs[16][136] -> per-wave 16-col MFMA
// tile -> fp8 hN + LDS-reduced asN/adN (ping-pong A<->B buffers).
// (r13: never chain blocks across XCDs. r6/r7: don't fuse the offs scan.)
// ---------------------------------------------------------------------------

#define LRELU(x) ((x) > 0.f ? (x) : 0.2f * (x))

typedef short bf16x8 __attribute__((ext_vector_type(8)));
typedef unsigned short u16x8 __attribute__((ext_vector_type(8)));
typedef float f32x4 __attribute__((ext_vector_type(4)));
typedef float f32x2 __attribute__((ext_vector_type(2)));

__device__ __forceinline__ unsigned short f2bf(float f) {
    unsigned int u = __float_as_uint(f);
    u = (u + 0x7fffu + ((u >> 16) & 1u)) >> 16;  // RNE
    return (unsigned short)u;
}
__device__ __forceinline__ float bf2f(unsigned short u) {
    return __uint_as_float((unsigned int)u << 16);
}
__device__ __forceinline__ unsigned char f2fp8(float f) {
    return (unsigned char)(__builtin_amdgcn_cvt_pk_fp8_f32(f, f, 0, false) & 0xff);
}
__device__ __forceinline__ f32x2 fp8pair(unsigned int u) {
    return __builtin_amdgcn_cvt_pk_f32_fp8(u, false);  // bytes 0,1
}

// fp8 h byte position for channel c: 2-head interleaved pairs, 1-head flat
template <int OUT, int HEADS>
__device__ __forceinline__ int hpos8(int c) {
    return (HEADS == 2) ? (2 * (c & 63) + (c >> 6)) : c;
}

// -- P1: bucket hist (2048-edge chunks) || transform0 || W pack || gstart ---

__global__ __launch_bounds__(256) void hist_t0_kernel(
    const int* __restrict__ dst, int* __restrict__ histT,
    int e, int G1, int NB, int n, int hist_blocks, int t0_blocks, int wp_blocks,
    const float* __restrict__ x, const float* __restrict__ W,
    const float* __restrict__ a_src, const float* __restrict__ a_dst,
    unsigned char* __restrict__ h, float* __restrict__ as_o,
    float* __restrict__ ad_o,
    const float* __restrict__ W1, const float* __restrict__ W2,
    unsigned short* __restrict__ Wf1, unsigned short* __restrict__ Wf2,
    const int* __restrict__ batch, int* __restrict__ gstart, int nGraphs) {
    __shared__ unsigned int hist[256];
    __shared__ float xs[2][8][8];
    const int t = threadIdx.x;
    if ((int)blockIdx.x < hist_blocks) {
        hist[t] = 0;
        __syncthreads();
        int base = blockIdx.x * 2048 + t * 8;
        int d[8];
        if (base + 8 <= e) {
            int4 x0 = *(const int4*)(dst + base);
            int4 x1 = *(const int4*)(dst + base + 4);
            d[0] = x0.x; d[1] = x0.y; d[2] = x0.z; d[3] = x0.w;
            d[4] = x1.x; d[5] = x1.y; d[6] = x1.z; d[7] = x1.w;
        } else {
#pragma unroll
            for (int j = 0; j < 8; j++) {
                int ij = base + j;
                d[j] = (ij < e) ? dst[ij] : -1;
            }
        }
#pragma unroll
        for (int j = 0; j < 8; j++) {
            if (d[j] >= 0) atomicAdd(&hist[d[j] >> 8], 1u);
        }
        __syncthreads();
        if (t < NB) histT[t * G1 + blockIdx.x] = (int)hist[t];
        return;
    }
    if ((int)blockIdx.x < hist_blocks + t0_blocks) {
        // ---- transform0 path: h(fp8)=x@W0, as/ad. 16 nodes/block ----
        const int bid2 = blockIdx.x - hist_blocks;
        const int tid = t & 127;
        const int half = t >> 7;
        const int node0 = bid2 * 16 + half * 8;

        for (int idx = tid; idx < 64; idx += 128) {
            int ni = idx >> 3, k = idx & 7;
            int ng = node0 + ni;
            xs[half][ni][k] = (ng < n) ? x[(size_t)ng * 8 + k] : 0.f;
        }
        __syncthreads();

        float acc[8];
#pragma unroll
        for (int i = 0; i < 8; i++) acc[i] = 0.f;
#pragma unroll
        for (int k = 0; k < 8; k++) {
            float wk = W[k * 128 + tid];
#pragma unroll
            for (int i = 0; i < 8; i++) acc[i] += xs[half][i][k] * wk;
        }

        const int lane = tid & 63;
        const int head = tid >> 6;
        const int pos = 2 * lane + head;  // 2-head interleaved fp8 byte pos
        const float av = a_src[tid];
        const float dv = a_dst[tid];
#pragma unroll
        for (int i = 0; i < 8; i++) {
            int ng = node0 + i;
            if (ng >= n) break;
            h[(size_t)ng * 128 + pos] = f2fp8(acc[i]);
            float ps = acc[i] * av, pd = acc[i] * dv;
            for (int off = 32; off; off >>= 1) {
                ps += __shfl_xor(ps, off, 64);
                pd += __shfl_xor(pd, off, 64);
            }
            if (lane == 0) {
                as_o[ng * 2 + head] = ps;
                ad_o[ng * 2 + head] = pd;
            }
        }
        return;
    }
    if ((int)blockIdx.x < hist_blocks + t0_blocks + wp_blocks) {
        // ---- W pack path ----
        const int n1 = 8 * 4 * 64;   // W1 fragment rows (OUT=128)
        const int n2 = 4 * 4 * 64;   // W2 fragment rows (OUT=64)
        int gid = (blockIdx.x - hist_blocks - t0_blocks) * 256 + t;
        if (gid < n1) {
            int idx = gid;
            int lane = idx & 63, ts = idx >> 6;
            int s = ts & 3, tt = ts >> 2;
            int quad = lane >> 4, cn = lane & 15;
#pragma unroll
            for (int j = 0; j < 8; j++)
                Wf1[idx * 8 + j] = f2bf(W1[(s * 32 + quad * 8 + j) * 128 + tt * 16 + cn]);
        } else if (gid < n1 + n2) {
            int idx = gid - n1;
            int lane = idx & 63, ts = idx >> 6;
            int s = ts & 3, tt = ts >> 2;
            int quad = lane >> 4, cn = lane & 15;
#pragma unroll
            for (int j = 0; j < 8; j++)
                Wf2[idx * 8 + j] = f2bf(W2[(s * 32 + quad * 8 + j) * 64 + tt * 16 + cn]);
        }
        return;
    }
    // ---- gstart path: graph boundaries of sorted batch ----
    int gid = (blockIdx.x - hist_blocks - t0_blocks - wp_blocks) * 256 + t;
    if (gid < n) {
        int bi = batch[gid];
        if (gid == 0) {
            for (int g = 0; g <= bi; g++) gstart[g] = 0;
        } else {
            int bp = batch[gid - 1];
            if (bi != bp)
                for (int g = bp + 1; g <= bi; g++) gstart[g] = gid;
        }
        if (gid == n - 1) {
            for (int g = bi + 1; g <= nGraphs; g++) gstart[g] = n;
        }
    }
}

// ---------------- generalized scan: 512 elements per block -----------------

__global__ __launch_bounds__(256) void scan2_block_kernel(
    const int* __restrict__ in, int* __restrict__ out,
    int* __restrict__ blockSums, int len) {
    __shared__ int lds[256];
    int t = threadIdx.x;
    int i0 = blockIdx.x * 512 + 2 * t;
    int v0 = (i0 < len) ? in[i0] : 0;
    int v1 = (i0 + 1 < len) ? in[i0 + 1] : 0;
    int s = v0 + v1;
    lds[t] = s;
    __syncthreads();
    for (int off = 1; off < 256; off <<= 1) {
        int u = (t >= off) ? lds[t - off] : 0;
        __syncthreads();
        lds[t] += u;
        __syncthreads();
    }
    int base = lds[t] - s;  // block-local exclusive for element i0
    if (i0 < len) out[i0] = base;
    if (i0 + 1 < len) out[i0 + 1] = base + v0;
    if (t == 255) blockSums[blockIdx.x] = lds[255];
}

// Every block redundantly scans blockSums (nb <= 256) and applies its base.
__global__ __launch_bounds__(256) void scan2_finalize_kernel(
    int* __restrict__ out, const int* __restrict__ blockSums, int len, int nb) {
    __shared__ int lds[256];
    int t = threadIdx.x;
    int v = (t < nb) ? blockSums[t] : 0;
    lds[t] = v;
    __syncthreads();
    for (int off = 1; off < 256; off <<= 1) {
        int u = (t >= off) ? lds[t - off] : 0;
        __syncthreads();
        lds[t] += u;
        __syncthreads();
    }
    const int bid = blockIdx.x;
    const int base = (bid > 0) ? lds[bid - 1] : 0;
    const int total = lds[nb - 1];
    int i0 = bid * 512 + 2 * t;
#pragma unroll
    for (int q = 0; q < 2; q++) {
        int i = i0 + q;
        if (i < len) out[i] += base;
        else if (i == len) out[len] = total;
    }
}

// -- P3: bucket partition (LDS ranks; offs column cached in LDS) ------------

__global__ __launch_bounds__(256) void bucket_scatter_kernel(
    const int* __restrict__ src, const int* __restrict__ dst,
    const int* __restrict__ offs, int* __restrict__ esrc,
    unsigned char* __restrict__ dsub8, int e, int G1, int NB) {
    __shared__ unsigned int hist[256];
    __shared__ int baseL[256];
    const int t = threadIdx.x;
    hist[t] = 0;
    if (t < NB) baseL[t] = offs[t * G1 + blockIdx.x];
    __syncthreads();
    int base = blockIdx.x * 2048 + t * 8;
    int d[8], s[8];
    if (base + 8 <= e) {
        int4 d0 = *(const int4*)(dst + base);
        int4 d1 = *(const int4*)(dst + base + 4);
        int4 s0 = *(const int4*)(src + base);
        int4 s1 = *(const int4*)(src + base + 4);
        d[0] = d0.x; d[1] = d0.y; d[2] = d0.z; d[3] = d0.w;
        d[4] = d1.x; d[5] = d1.y; d[6] = d1.z; d[7] = d1.w;
        s[0] = s0.x; s[1] = s0.y; s[2] = s0.z; s[3] = s0.w;
        s[4] = s1.x; s[5] = s1.y; s[6] = s1.z; s[7] = s1.w;
    } else {
#pragma unroll
        for (int j = 0; j < 8; j++) {
            int ij = base + j;
            bool v = ij < e;
            d[j] = v ? dst[ij] : -1;
            s[j] = v ? src[ij] : 0;
        }
    }
    unsigned lr[8];
#pragma unroll
    for (int j = 0; j < 8; j++) {
        lr[j] = (d[j] >= 0) ? atomicAdd(&hist[d[j] >> 8], 1u) : 0u;
    }
#pragma unroll
    for (int j = 0; j < 8; j++) {
        if (d[j] >= 0) {
            int pos = baseL[d[j] >> 8] + (int)lr[j];
            esrc[pos] = s[j];
            dsub8[pos] = (unsigned char)(d[j] & 255);
        }
    }
}

// -- P4: per-bucket (256 nodes) CSR finalize: count -> scan -> row_ptr -> col

__global__ __launch_bounds__(256) void bucket_csr_kernel(
    const int* __restrict__ offs, const unsigned char* __restrict__ dsub8,
    const int* __restrict__ esrc, int* __restrict__ row_ptr,
    int* __restrict__ col, int G1, int n) {
    __shared__ unsigned int cnt[256];
    __shared__ int rp[256];
    int t = threadIdx.x;
    int b = blockIdx.x;
    cnt[t] = 0;
    __syncthreads();
    int bs = offs[b * G1];
    int be = offs[(b + 1) * G1];
    for (int i = bs + t; i < be; i += 256) {
        atomicAdd(&cnt[dsub8[i]], 1u);
    }
    __syncthreads();
    int v = (int)cnt[t];
    rp[t] = v;
    __syncthreads();
    for (int off = 1; off < 256; off <<= 1) {
        int u = (t >= off) ? rp[t - off] : 0;
        __syncthreads();
        rp[t] += u;
        __syncthreads();
    }
    int excl = rp[t] - v;
    int node = b * 256 + t;
    if (node <= n) row_ptr[node] = bs + excl;  // node==n lands here too (E)
    __syncthreads();
    cnt[t] = (unsigned)excl;  // running cursors
    __syncthreads();
    for (int i = bs + t; i < be; i += 256) {
        int sub = dsub8[i];
        unsigned r = atomicAdd(&cnt[sub], 1u);
        col[bs + (int)r] = esrc[i];
    }
}

// -- agg2t: 2-head agg (2 nodes/wave, 16 nodes/block) + FUSED next-layer ----
// MFMA transform. r9 staged-broadcast consume, w0/w1 packed in one float2
// LDS array (2 LDS reads/edge), 8 loads in flight.

template <int OUT2, int HEADS2>
__global__ __launch_bounds__(512) void agg2t_kernel(
    const int* __restrict__ row_ptr, const int* __restrict__ col,
    const unsigned char* __restrict__ h, const float2* __restrict__ as2,
    const float2* __restrict__ ad2, const float* __restrict__ bias,
    const unsigned short* __restrict__ Wf, const float* __restrict__ aN_src,
    const float* __restrict__ aN_dst, unsigned char* __restrict__ hN,
    float* __restrict__ asN, float* __restrict__ adN, int n) {
    __shared__ float2 w01l[8][2][32];
    __shared__ unsigned sofl[8][2][32];
    __shared__ unsigned short xs[16][136];   // 272B row stride: b128-aligned
    __shared__ float asP[16][8], adP[16][8];
    const int w = threadIdx.x >> 6;
    const int lane = threadIdx.x & 63;
    const int half = lane >> 5, l = lane & 31;
    const int node0 = blockIdx.x * 16;
    const int mloc = w * 2 + half;
    const int node = node0 + mloc;
    const bool active = node < n;

    // ---------------- aggregation (2-head, fp8 h) ----------------
    int beg = 0, deg = 0;
    float2 adv = make_float2(0.f, 0.f);
    float den0 = 0.f, den1 = 0.f;
    float a0 = 0.f, a1 = 0.f, a2 = 0.f, a3 = 0.f;
    if (active) {
        beg = row_ptr[node];
        deg = row_ptr[node + 1] - beg;
        adv = ad2[node];
        float2 avs = as2[node];
        float w0s = __expf(LRELU(avs.x + adv.x));
        float w1s = __expf(LRELU(avs.y + adv.y));
        unsigned us = *(const unsigned*)(h + ((size_t)node << 7) + 4 * l);
        f32x2 p0 = fp8pair(us & 0xffffu);
        f32x2 p1 = fp8pair(us >> 16);
        a0 = w0s * p0.x; a1 = w1s * p0.y;
        a2 = w0s * p1.x; a3 = w1s * p1.y;
        den0 = w0s; den1 = w1s;
    }
    int dmax = deg;
    for (int off = 32; off; off >>= 1) dmax = max(dmax, __shfl_xor(dmax, off, 64));

    for (int base = 0; base < dmax; base += 32) {
        int cnt = deg - base;
        cnt = cnt < 0 ? 0 : (cnt > 32 ? 32 : cnt);
        float w0 = 0.f, w1 = 0.f;
        unsigned so = 0;
        if (l < cnt) {
            int s = col[beg + base + l];
            float2 av = as2[s];
            w0 = __expf(LRELU(av.x + adv.x));
            w1 = __expf(LRELU(av.y + adv.y));
            so = (unsigned)s << 7;
        }
        float t0 = w0, t1 = w1;
        for (int off = 16; off; off >>= 1) {
            t0 += __shfl_xor(t0, off, 64);
            t1 += __shfl_xor(t1, off, 64);
        }
        den0 += t0; den1 += t1;
        w01l[w][half][l] = make_float2(w0, w1);
        sofl[w][half][l] = so;  // same-wave LDS RAW: compiler emits lgkmcnt

        int jmax = dmax - base;
        jmax = jmax > 32 ? 32 : jmax;
        for (int j = 0; j < jmax; j += 8) {
            unsigned u[8];
#pragma unroll
            for (int k = 0; k < 8; k++) {
                unsigned so_k = sofl[w][half][j + k];  // uniform per half
                u[k] = *(const unsigned*)(h + so_k + 4 * l);
            }
            float2 W01[8];
#pragma unroll
            for (int k = 0; k < 8; k++) W01[k] = w01l[w][half][j + k];
#pragma unroll
            for (int k = 0; k < 8; k++) {
                f32x2 p0 = fp8pair(u[k] & 0xffffu);
                f32x2 p1 = fp8pair(u[k] >> 16);
                a0 += W01[k].x * p0.x; a1 += W01[k].y * p0.y;
                a2 += W01[k].x * p1.x; a3 += W01[k].y * p1.y;
            }
        }
    }

    // epilogue -> LDS (bf16; same quantization as old global xb round-trip)
    if (active) {
        float2 bA = *(const float2*)(bias + 2 * l);
        float2 bB = *(const float2*)(bias + 64 + 2 * l);
        float r0 = 1.f / (den0 + 1e-16f), r1 = 1.f / (den1 + 1e-16f);
        float o0 = a0 * r0 + bA.x;  // ch2l   h0
        float o1 = a1 * r1 + bB.x;  // ch2l   h1
        float o2 = a2 * r0 + bA.y;  // ch2l+1 h0
        float o3 = a3 * r1 + bB.y;  // ch2l+1 h1
        o0 = o0 > 0.f ? o0 : expm1f(o0);
        o1 = o1 > 0.f ? o1 : expm1f(o1);
        o2 = o2 > 0.f ? o2 : expm1f(o2);
        o3 = o3 > 0.f ? o3 : expm1f(o3);
        *(unsigned*)&xs[mloc][2 * l] = (unsigned)f2bf(o0) | ((unsigned)f2bf(o2) << 16);
        *(unsigned*)&xs[mloc][64 + 2 * l] = (unsigned)f2bf(o1) | ((unsigned)f2bf(o3) << 16);
    } else {
        *(unsigned*)&xs[mloc][2 * l] = 0;
        *(unsigned*)&xs[mloc][64 + 2 * l] = 0;
    }
    __syncthreads();

    // ---------------- fused transform: hN = xs @ Wf ----------------
    constexpr int T2 = OUT2 / 16, S = 4;  // K = 128
    const int quad = lane >> 4, colc = lane & 15;
    if (w < T2) {
        bf16x8 a[S];
#pragma unroll
        for (int s = 0; s < S; s++)
            a[s] = *(const bf16x8*)&xs[colc][quad * 8 + s * 32];
        f32x4 acc = (f32x4){0.f, 0.f, 0.f, 0.f};
#pragma unroll
        for (int s = 0; s < S; s++) {
            bf16x8 b = *(const bf16x8*)(Wf + ((size_t)(w * S + s) * 64 + lane) * 8);
            acc = __builtin_amdgcn_mfma_f32_16x16x32_bf16(a[s], b, acc, 0, 0, 0);
        }
        const int pos = hpos8<OUT2, HEADS2>(w * 16 + colc);
#pragma unroll
        for (int r = 0; r < 4; r++) {
            int m = node0 + quad * 4 + r;
            if (m < n) hN[(size_t)m * OUT2 + pos] = f2fp8(acc[r]);
        }
        const float av = aN_src[w * 16 + colc];
        const float dv = aN_dst[w * 16 + colc];
#pragma unroll
        for (int r = 0; r < 4; r++) {
            float sp = acc[r] * av, dp = acc[r] * dv;
            for (int off = 8; off; off >>= 1) {
                sp += __shfl_xor(sp, off, 64);
                dp += __shfl_xor(dp, off, 64);
            }
            if (colc == 0) {
                asP[quad * 4 + r][w] = sp;
                adP[quad * 4 + r][w] = dp;
            }
        }
    }
    __syncthreads();
    const int tt = threadIdx.x;
    if (tt < 16 * HEADS2) {
        int m = tt & 15, head = tt >> 4;
        int node2 = node0 + m;
        if (node2 < n) {
            float s = 0.f, d = 0.f;
#pragma unroll
            for (int ww = 0; ww < 4; ww++) {
                s += asP[m][head * 4 + ww];
                d += adP[m][head * 4 + ww];
            }
            asN[node2 * HEADS2 + head] = s;
            adN[node2 * HEADS2 + head] = d;
        }
    }
}

// ------- GAT aggregation, 1 head (fp8 h, layer 2): two nodes per wave ------
// r9 staged-broadcast consume, 8 loads in flight. Output bf16.

__global__ __launch_bounds__(256) void agg1_kernel(
    const int* __restrict__ row_ptr, const int* __restrict__ col,
    const unsigned char* __restrict__ h, const float* __restrict__ as1,
    const float* __restrict__ ad1, const float* __restrict__ bias,
    unsigned short* __restrict__ out, int n) {
    __shared__ float wl[4][2][32];
    __shared__ unsigned sofl[4][2][32];
    const int w = threadIdx.x >> 6;
    const int lane = threadIdx.x & 63;
    const int half = lane >> 5, l = lane & 31;
    const int node = blockIdx.x * 8 + w * 2 + half;
    const bool active = node < n;

    int beg = 0, deg = 0;
    float adv = 0.f, den = 0.f, a0 = 0.f, a2 = 0.f;
    if (active) {
        beg = row_ptr[node];
        deg = row_ptr[node + 1] - beg;
        adv = ad1[node];
        float ws = __expf(LRELU(as1[node] + adv));
        unsigned us = *(const unsigned short*)(h + ((size_t)node << 6) + 2 * l);
        f32x2 p = fp8pair(us);
        a0 = ws * p.x;
        a2 = ws * p.y;
        den = ws;
    }
    int dmax = deg;
    for (int off = 32; off; off >>= 1) dmax = max(dmax, __shfl_xor(dmax, off, 64));

    for (int base = 0; base < dmax; base += 32) {
        int cnt = deg - base;
        cnt = cnt < 0 ? 0 : (cnt > 32 ? 32 : cnt);
        float w0 = 0.f;
        unsigned so = 0;
        if (l < cnt) {
            int s = col[beg + base + l];
            w0 = __expf(LRELU(as1[s] + adv));
            so = (unsigned)s << 6;
        }
        float t = w0;
        for (int off = 16; off; off >>= 1) t += __shfl_xor(t, off, 64);
        den += t;
        wl[w][half][l] = w0;
        sofl[w][half][l] = so;

        int jmax = dmax - base;
        jmax = jmax > 32 ? 32 : jmax;
        for (int j = 0; j < jmax; j += 8) {
            unsigned u[8];
#pragma unroll
            for (int k = 0; k < 8; k++) {
                unsigned so_k = sofl[w][half][j + k];
                u[k] = *(const unsigned short*)(h + so_k + 2 * l);
            }
            float W0[8];
#pragma unroll
            for (int k = 0; k < 8; k++) W0[k] = wl[w][half][j + k];
#pragma unroll
            for (int k = 0; k < 8; k++) {
                f32x2 p = fp8pair(u[k]);
                a0 += W0[k] * p.x;
                a2 += W0[k] * p.y;
            }
        }
    }

    if (active) {
        float2 bA = *(const float2*)(bias + 2 * l);
        float r = 1.f / (den + 1e-16f);
        float o0 = a0 * r + bA.x;
        float o2 = a2 * r + bA.y;
        unsigned hv = (unsigned)f2bf(o0) | ((unsigned)f2bf(o2) << 16);
        *(unsigned*)(out + (size_t)node * 64 + 2 * l) = hv;
    }
}

// ------- MLP head (pool fused): 512 threads/block, one block per graph -----

__global__ __launch_bounds__(512) void mlp_kernel(
    const unsigned short* __restrict__ xbuf, const int* __restrict__ gstart,
    const float* __restrict__ obs,
    const float* __restrict__ Ws1, const float* __restrict__ bs1,
    const float* __restrict__ ln_g, const float* __restrict__ ln_b,
    const float* __restrict__ Ws2, const float* __restrict__ bs2,
    const float* __restrict__ Wa, const float* __restrict__ ba,
    const float* __restrict__ Wc, const float* __restrict__ bc,
    float* __restrict__ out_logits, float* __restrict__ out_value) {
    int b = blockIdx.x;
    int t = threadIdx.x;
    __shared__ float comb[192];
    __shared__ float red[512];
    __shared__ float red2[8][64];
    __shared__ float hs[256];

    const int gs = gstart[b];
    const int ge = gstart[b + 1];

    // ---- pool: 64 rowgroups (8/wave) x 8 chunks of ushort8 ----
    {
        const int w = t >> 6, lane = t & 63;
        const int rg = w * 8 + (lane >> 3);
        const int sub = lane & 7;
        float acc[8];
#pragma unroll
        for (int j = 0; j < 8; j++) acc[j] = 0.f;
        for (int i = gs + rg; i < ge; i += 64) {
            u16x8 v = *(const u16x8*)(xbuf + (size_t)i * 64 + sub * 8);
#pragma unroll
            for (int j = 0; j < 8; j++) acc[j] += bf2f(v[j]);
        }
#pragma unroll
        for (int off = 8; off <= 32; off <<= 1) {
#pragma unroll
            for (int j = 0; j < 8; j++) acc[j] += __shfl_xor(acc[j], off, 64);
        }
        if (lane < 8) {
#pragma unroll
            for (int j = 0; j < 8; j++) red2[w][lane * 8 + j] = acc[j];
        }
    }
    __syncthreads();
    {
        float cdiv = fmaxf((float)(ge - gs), 1.f);
        if (t < 64) {
            float s = 0.f;
#pragma unroll
            for (int w = 0; w < 8; w++) s += red2[w][t];
            comb[t] = s / cdiv;
        } else if (t < 192) {
            comb[t] = obs[b * 128 + (t - 64)];
        }
    }
    __syncthreads();

    const int t256 = t & 255;
    const int khalf = t >> 8;

    // ---- fc1: k split 2x96 ----
    {
        float accA = 0.f, accB = 0.f;
        int k0 = khalf * 96;
#pragma unroll 4
        for (int k = k0; k < k0 + 96; k += 2) {
            accA += comb[k] * Ws1[k * 256 + t256];
            accB += comb[k + 1] * Ws1[(k + 1) * 256 + t256];
        }
        red[t] = accA + accB;
    }
    __syncthreads();
    float acc = 0.f;
    if (t < 256) acc = bs1[t] + red[t] + red[t + 256];
    __syncthreads();

    // ---- LayerNorm over 256 ----
    red[t] = (t < 256) ? acc : 0.f;
    __syncthreads();
    for (int off = 128; off; off >>= 1) {
        if (t < off) red[t] += red[t + off];
        __syncthreads();
    }
    float mu = red[0] / 256.f;
    __syncthreads();
    float d = acc - mu;
    red[t] = (t < 256) ? d * d : 0.f;
    __syncthreads();
    for (int off = 128; off; off >>= 1) {
        if (t < off) red[t] += red[t + off];
        __syncthreads();
    }
    float var = red[0] / 256.f;
    if (t < 256) {
        float hn = d * rsqrtf(var + 1e-5f) * ln_g[t] + ln_b[t];
        hs[t] = hn > 0.f ? hn : 0.f;
    }
    __syncthreads();

    // ---- fc2: k split 2x128 ----
    {
        float a2A = 0.f, a2B = 0.f;
        int k0 = khalf * 128;
#pragma unroll 4
        for (int k = k0; k < k0 + 128; k += 2) {
            a2A += hs[k] * Ws2[k * 256 + t256];
            a2B += hs[k + 1] * Ws2[(k + 1) * 256 + t256];
        }
        red[t] = a2A + a2B;
    }
    __syncthreads();
    float acc2 = 0.f;
    if (t < 256) {
        acc2 = bs2[t] + red[t] + red[t + 256];
        acc2 = acc2 > 0.f ? acc2 : 0.f;
    }
    __syncthreads();
    if (t < 256) hs[t] = acc2;
    __syncthreads();

    // ---- logits: 16 outs x 32 k-chunks of 8 + LDS tree ----
    {
        int o = t & 15, ck = t >> 4;
        float p = 0.f;
#pragma unroll
        for (int k = 0; k < 8; k++)
            p += hs[ck * 8 + k] * Wa[(ck * 8 + k) * 16 + o];
        red[t] = p;
    }
    __syncthreads();
    for (int off = 16; off >= 1; off >>= 1) {
        if ((t >> 4) < off) red[t] += red[t + off * 16];
        __syncthreads();
    }
    if (t < 16) out_logits[b * 16 + t] = red[t] + ba[t];
    __syncthreads();

    // ---- value: full-width dot + tree over 512 ----
    red[t] = (t < 256) ? hs[t] * Wc[t] : 0.f;
    __syncthreads();
    for (int off = 256; off; off >>= 1) {
        if (t < off) red[t] += red[t + off];
        __syncthreads();
    }
    if (t == 0) out_value[b] = red[0] + bc[0];
}

// ---------------------------------------------------------------------------

extern "C" void kernel_launch(void* const* d_in, const int* in_sizes, int n_in,
                              void* d_out, int out_size, void* d_ws, size_t ws_size,
                              hipStream_t stream) {
    const float* obs    = (const float*)d_in[0];
    const float* nf     = (const float*)d_in[1];
    const int*   ei     = (const int*)d_in[2];
    const int*   batch  = (const int*)d_in[3];
    const float* W0     = (const float*)d_in[4];
    const float* a_src0 = (const float*)d_in[5];
    const float* a_dst0 = (const float*)d_in[6];
    const float* b0     = (const float*)d_in[7];
    const float* W1     = (const float*)d_in[8];
    const float* a_src1 = (const float*)d_in[9];
    const float* a_dst1 = (const float*)d_in[10];
    const float* b1     = (const float*)d_in[11];
    const float* W2     = (const float*)d_in[12];
    const float* a_src2 = (const float*)d_in[13];
    const float* a_dst2 = (const float*)d_in[14];
    const float* b2     = (const float*)d_in[15];
    const float* Ws1    = (const float*)d_in[16];
    const float* bs1    = (const float*)d_in[17];
    const float* ln_g   = (const float*)d_in[18];
    const float* ln_b   = (const float*)d_in[19];
    const float* Ws2    = (const float*)d_in[20];
    const float* bs2    = (const float*)d_in[21];
    const float* Wa     = (const float*)d_in[22];
    const float* ba     = (const float*)d_in[23];
    const float* Wc     = (const float*)d_in[24];
    const float* bc     = (const float*)d_in[25];

    const int N = in_sizes[3];
    const int E = in_sizes[2] / 2;
    const int B = in_sizes[0] / 128;
    const int* src = ei;
    const int* dstp = ei + E;

    // workspace carve (256B aligned)
    char* p = (char*)d_ws;
    auto alloc = [&](size_t bytes) -> void* {
        void* r = (void*)p;
        p += (bytes + 255) & ~(size_t)255;
        return r;
    };
    const int G1 = (E + 2047) / 2048;       // edge chunks (2048/block)
    const int NB = (N + 255) >> 8;          // dst buckets of 256 (n <= 65536)
    const int L  = NB * G1;                 // histT length
    int*   row_ptr   = (int*)alloc((size_t)(N + 1) * 4);
    int*   col       = (int*)alloc((size_t)E * 4);
    int*   esrc      = (int*)alloc((size_t)E * 4);           // bucketed src
    unsigned char* dsub8 = (unsigned char*)alloc((size_t)E); // bucketed dst&255
    int*   histT     = (int*)alloc((size_t)L * 4);           // [b][g]
    int*   offs      = (int*)alloc((size_t)(L + 1) * 4);
    unsigned char* hbufA = (unsigned char*)alloc((size_t)N * 128);  // fp8 ping
    unsigned char* hbufB = (unsigned char*)alloc((size_t)N * 128);  // fp8 pong
    unsigned short* xbuf = (unsigned short*)alloc((size_t)N * 64 * 2);  // bf16
    float* as0       = (float*)alloc((size_t)N * 2 * 4);
    float* ad0       = (float*)alloc((size_t)N * 2 * 4);
    float* as1       = (float*)alloc((size_t)N * 2 * 4);
    float* ad1       = (float*)alloc((size_t)N * 2 * 4);
    float* as2v      = (float*)alloc((size_t)N * 4);
    float* ad2v      = (float*)alloc((size_t)N * 4);
    unsigned short* Wf1 = (unsigned short*)alloc((size_t)8 * 4 * 64 * 8 * 2);
    unsigned short* Wf2 = (unsigned short*)alloc((size_t)4 * 4 * 64 * 8 * 2);
    int* gstart      = (int*)alloc((size_t)(B + 1) * 4);
    int* blockSums   = (int*)alloc((size_t)1024 * 4);

    float* out_logits = (float*)d_out;
    float* out_value  = out_logits + (size_t)B * 16;

    // ---- P1: hist || transform0 || W pack || gstart (1 dispatch) ----
    int t0_blocks = (N + 15) / 16;
    int wp_blocks = (8 * 4 * 64 + 4 * 4 * 64 + 255) / 256;
    int gb_blocks = (N + 255) / 256;
    hist_t0_kernel<<<G1 + t0_blocks + wp_blocks + gb_blocks, 256, 0, stream>>>(
        dstp, histT, E, G1, NB, N, G1, t0_blocks, wp_blocks,
        nf, W0, a_src0, a_dst0, hbufA, as0, ad0,
        W1, W2, Wf1, Wf2, batch, gstart, B);

    // ---- scanA over histT -> offs (2 small dispatches) ----
    int nbA = (L + 511) / 512;
    scan2_block_kernel<<<nbA, 256, 0, stream>>>(histT, offs, blockSums, L);
    scan2_finalize_kernel<<<(L + 1 + 511) / 512, 256, 0, stream>>>(offs, blockSums, L, nbA);

    // ---- P3 bucket partition (LDS-cached offs col) + P4 finalize ----
    bucket_scatter_kernel<<<G1, 256, 0, stream>>>(src, dstp, offs, esrc, dsub8, E, G1, NB);
    bucket_csr_kernel<<<NB, 256, 0, stream>>>(offs, dsub8, esrc, row_ptr, col, G1, N);

    // ---- GAT layer 0 agg + fused transform1 (hA,as0 -> hB,as1) ----
    agg2t_kernel<128, 2><<<(N + 15) / 16, 512, 0, stream>>>(
        row_ptr, col, hbufA, (const float2*)as0, (const float2*)ad0, b0,
        Wf1, a_src1, a_dst1, hbufB, as1, ad1, N);

    // ---- GAT layer 1 agg + fused transform2 (hB,as1 -> hA,as2) ----
    agg2t_kernel<64, 1><<<(N + 15) / 16, 512, 0, stream>>>(
        row_ptr, col, hbufB, (const float2*)as1, (const float2*)ad1, b1,
        Wf2, a_src2, a_dst2, hbufA, as2v, ad2v, N);

    // ---- GAT layer 2 aggregation -> xbuf ----
    agg1_kernel<<<(N + 7) / 8, 256, 0, stream>>>(
        row_ptr, col, hbufA, as2v, ad2v, b2, xbuf, N);

    // ---- MLP head with fused mean-pool (1 dispatch, no atomics) ----
    mlp_kernel<<<B, 512, 0, stream>>>(xbuf, gstart, obs, Ws1, bs1, ln_g, ln_b,
                                      Ws2, bs2, Wa, ba, Wc, bc,
                                      out_logits, out_value);
}